// Round 5
// baseline (112.228 us; speedup 1.0000x reference)
//
#include <hip/hip_runtime.h>
#include <hip/hip_bf16.h>

#define B_ 4
#define T_ 256
#define S_ 256
#define D_ 512
#define TB 2   // t's per attention block

typedef __bf16 bf16x8 __attribute__((ext_vector_type(8)));
typedef float  floatx4 __attribute__((ext_vector_type(4)));
typedef float  floatx2 __attribute__((ext_vector_type(2)));

#define C2F 2.885390081777926f  // 2*log2(e)

static __device__ __forceinline__ unsigned short f2bf(float x) {
    __hip_bfloat16 h = __float2bfloat16(x);
    return *reinterpret_cast<unsigned short*>(&h);
}
static __device__ __forceinline__ float asf(unsigned int u) {
    float f; __builtin_memcpy(&f, &u, 4); return f;
}
static __device__ __forceinline__ float clamp_pos(float x) {
    // keep strictly positive and finite: [1e-15, 1e15]
    return fminf(fmaxf(x, 1e-15f), 1e15f);
}

// ---------------------------------------------------------------------------
// Fragment-order layout (K=512 => 16 k-blocks of 32):
//   tile(mblk,kblk) = mblk*16 + kblk;  lane = (m&15) | (((k>>3)&3)<<4)
//   addr = (tile*64 + lane)*8 + (k&7)
// ---------------------------------------------------------------------------

__global__ __launch_bounds__(256) void prep(
    const float* __restrict__ output, const float* __restrict__ context,
    const float* __restrict__ Wq, const float* __restrict__ Wc,
    const float* __restrict__ Wout,
    unsigned short* __restrict__ out_f, unsigned short* __restrict__ ctx_f,
    unsigned short* __restrict__ Wq_f, unsigned short* __restrict__ Wc_f,
    unsigned short* __restrict__ WoT_f, unsigned short* __restrict__ WoB_f)
{
    const int tid = threadIdx.x;
    const int z = blockIdx.z;

    if (z >= 4) {
        const float* src = (z == 4) ? output : context;
        unsigned short* dst = (z == 4) ? out_f : ctx_f;
        const int bid  = blockIdx.y * 16 + blockIdx.x;   // 0..255
        const int tile = bid * 4 + (tid >> 6);           // 0..1023
        const int lane = tid & 63;
        const int mblk = tile >> 4, kblk = tile & 15;
        const float* s = src + (size_t)(mblk * 16 + (lane & 15)) * 512
                             + kblk * 32 + (lane >> 4) * 8;
        float4 a = *(const float4*)s;
        float4 b = *(const float4*)(s + 4);
        uint4 pk;
        pk.x = (unsigned)f2bf(a.x) | ((unsigned)f2bf(a.y) << 16);
        pk.y = (unsigned)f2bf(a.z) | ((unsigned)f2bf(a.w) << 16);
        pk.z = (unsigned)f2bf(b.x) | ((unsigned)f2bf(b.y) << 16);
        pk.w = (unsigned)f2bf(b.z) | ((unsigned)f2bf(b.w) << 16);
        *(uint4*)(dst + (size_t)tile * 512 + lane * 8) = pk;
        return;
    }

    const float* W; unsigned short* WF; int krow0;
    if      (z == 0) { W = Wq;   WF = Wq_f;  krow0 = 0;   }
    else if (z == 1) { W = Wc;   WF = Wc_f;  krow0 = 0;   }
    else if (z == 2) { W = Wout; WF = WoT_f; krow0 = 0;   }
    else             { W = Wout; WF = WoB_f; krow0 = 512; }

    const int n0 = blockIdx.x * 32;
    const int k0 = blockIdx.y * 32;

    __shared__ float tile[32][33];
    const int c = tid & 31, r = tid >> 5;
    #pragma unroll
    for (int i = 0; i < 4; ++i)
        tile[r + 8 * i][c] = W[(size_t)(krow0 + k0 + r + 8 * i) * 512 + n0 + c];
    __syncthreads();
    #pragma unroll
    for (int i = 0; i < 4; ++i) {
        const int n = n0 + r + 8 * i;
        const int k = k0 + c;
        const int tl = (n >> 4) * 16 + (k >> 5);
        const int ln = (n & 15) | (((k >> 3) & 3) << 4);
        WF[((size_t)tl * 64 + ln) * 8 + (k & 7)] = f2bf(tile[c][r + 8 * i]);
    }
}

// ---------------------------------------------------------------------------
// MFMA bf16 GEMM from fragment-order inputs. Wave tile = 16m x 64n:
// 1 A-load + 4 B-loads -> 4 MFMAs per k-block (was 3 loads -> 2 MFMAs):
// higher MFMA density per issue slot, half the A-load redundancy.
// Epilogue modes:
//   1: H = clamp(exp2(C2F*(acc+bq[col])), 1e-15, 1e15)  fp32 (B,T,D)
//   3: W = clamp(exp2(+C2F*acc) * rcp(v[col]), +-1e20)  bf16
//      -> layout [b][d>>3][s][8]   (W = e^{2u}/v;  v*sigmoid = 1/(1/v + H*W))
//   4: fp32 acc + aux[col]                 (OB = output@Wout_bot + bout)
//   5: bf16 acc, natural [row][col]        (CWb = context@Wout_top)
// ---------------------------------------------------------------------------
struct GArgs {
    const unsigned short* Af;
    const unsigned short* Bf;
    const float* aux;    // bias (modes 1,4) or v (mode 3)
    void* C;
    int mode;
};

__global__ __launch_bounds__(256) void gemm2(GArgs g0, GArgs g1, GArgs g2, GArgs g3)
{
    const int z = blockIdx.z;
    GArgs g = (z == 0) ? g0 : (z == 1) ? g1 : (z == 2) ? g2 : g3;

    const int tid  = threadIdx.x;
    const int wave = tid >> 6, lane = tid & 63;
    const int l15  = lane & 15, quad = lane >> 4;
    const int mblk = blockIdx.y * 4 + wave;      // 0..63
    const int nb0  = blockIdx.x * 4;             // 0..28

    const unsigned short* Ap = g.Af + ((size_t)mblk * 16 * 64 + lane) * 8;
    const unsigned short* Bp = g.Bf + ((size_t)nb0 * 16 * 64 + lane) * 8;

    floatx4 acc[4];
    #pragma unroll
    for (int i = 0; i < 4; ++i) acc[i] = (floatx4){0.f, 0.f, 0.f, 0.f};

    #pragma unroll 4
    for (int k = 0; k < 16; ++k) {
        bf16x8 a  = *(const bf16x8*)(Ap + k * 512);
        #pragma unroll
        for (int ni = 0; ni < 4; ++ni) {
            bf16x8 b = *(const bf16x8*)(Bp + (size_t)ni * 16 * 512 + k * 512);
            acc[ni] = __builtin_amdgcn_mfma_f32_16x16x32_bf16(a, b, acc[ni], 0, 0, 0);
        }
    }

    #pragma unroll
    for (int ni = 0; ni < 4; ++ni) {
        const int col = (nb0 + ni) * 16 + l15;
        const int rbase = mblk * 16 + quad * 4;
        if (g.mode == 1) {
            float* Cf = (float*)g.C;
            float bv = g.aux[col];
            #pragma unroll
            for (int r = 0; r < 4; ++r) {
                float hh = __builtin_amdgcn_exp2f(C2F * (acc[ni][r] + bv));
                Cf[(size_t)(rbase + r) * 512 + col] = clamp_pos(hh);
            }
        } else if (g.mode == 3) {
            unsigned short* Cb = (unsigned short*)g.C;
            float rv = __builtin_amdgcn_rcpf(g.aux[col]);   // 1/v_col
            rv = fminf(fmaxf(rv, -1e30f), 1e30f);
            #pragma unroll
            for (int r = 0; r < 4; ++r) {
                int row = rbase + r, bb = row >> 8, ss = row & 255;
                float ww = __builtin_amdgcn_exp2f(C2F * acc[ni][r]) * rv;
                ww = fminf(fmaxf(ww, -1e20f), 1e20f);
                Cb[((size_t)(bb * 64 + (col >> 3)) * 256 + ss) * 8 + (col & 7)]
                    = f2bf(ww);
            }
        } else if (g.mode == 5) {
            unsigned short* Cb = (unsigned short*)g.C;
            #pragma unroll
            for (int r = 0; r < 4; ++r)
                Cb[(size_t)(rbase + r) * 512 + col] = f2bf(acc[ni][r]);
        } else {   // mode 4
            float* Cf = (float*)g.C;
            float bv = g.aux[col];
            #pragma unroll
            for (int r = 0; r < 4; ++r)
                Cf[(size_t)(rbase + r) * 512 + col] = acc[ni][r] + bv;
        }
    }
}

// ---------------------------------------------------------------------------
// Fused score + masked softmax + out-projection. 512 threads (8 waves).
// Score: v*sigmoid(-2(w+u)) = 1/(1/v + H*W),  H=e^{2w} (t,d), W=e^{2u}/v (s,d).
// x = iv + H*W is single-signed -> no cancellation. Pair combine, ONE rcp:
//   1/x0 + 1/x1 = (x0+x1) * rcp(x0*x1)
// x-pairs computed with PACKED fp32 (v_pk_fma_f32): all operand pairs are
// naturally adjacent (float4 LDS slices, bf16-unpack pairs) -> no movs.
// launch_bounds (512,4): ~128 VGPR headroom, no spill risk (the (512,8)
// 64-VGPR cap in the prior round risked scratch spills in the score loop).
// Softmax: p = exp2(-C2F*A) directly (shift-invariance).
// Out-proj: thread owns 4 consecutive d's x one s-quarter -> 8B/lane loads.
// XCD swizzle: chunk so each XCD keeps one b-half's streams in its L2.
// ---------------------------------------------------------------------------
__global__ __launch_bounds__(512, 4) void attn_fused(
    const float* __restrict__ Hb,             // (B,T,D) fp32  e^{2w}
    const unsigned short* __restrict__ Wb,    // (B,D/8,S,8) bf16  e^{2u}/v
    const unsigned short* __restrict__ CWb,   // (B,S,D) bf16
    const float* __restrict__ OB,             // (B,T,D) fp32
    const int*   __restrict__ mask,           // (B,S)
    const float* __restrict__ v,              // (D)
    float* __restrict__ attn_out,             // (B,T,S) fp32
    float* __restrict__ out)                  // (B,T,D) fp32
{
    // bijective XCD chunk swizzle (512 % 8 == 0)
    const int bid = blockIdx.x;
    const int bg  = (bid & 7) * (B_ * T_ / TB / 8) + (bid >> 3);
    const int b   = bg / (T_ / TB);
    const int t0  = (bg % (T_ / TB)) * TB;
    const int tid = threadIdx.x;
    const int s   = tid & 255;
    const int h   = tid >> 8;    // 0..1  (d-half in score)

    __shared__ float  w_s[TB][D_];       // 4 KB (H rows)
    __shared__ float  v_s[D_];           // 2 KB (1/v)
    __shared__ float2 part[2][256];      // 4 KB
    __shared__ float2 wred[4];
    __shared__ float  a_s[TB][256];      // 2 KB
    __shared__ float  mixp[4][TB][D_];   // 16 KB

    w_s[0][tid] = Hb[(size_t)(b * T_ + t0 + 0) * D_ + tid];
    w_s[1][tid] = Hb[(size_t)(b * T_ + t0 + 1) * D_ + tid];
    {
        float iv = __builtin_amdgcn_rcpf(v[tid]);
        v_s[tid] = fminf(fmaxf(iv, -1e30f), 1e30f);
    }
    __syncthreads();

    float acc0 = 0.f, acc1 = 0.f;
    const uint4* wb4 = (const uint4*)(Wb + ((size_t)(b * 64 + h * 32) * 256 + s) * 8);

    #pragma unroll 4
    for (int dd = 0; dd < 32; ++dd) {
        uint4 ww = wb4[(size_t)dd * 256];   // 16B coalesced across s-lanes
        floatx2 W01 = {asf(ww.x << 16), asf(ww.x & 0xffff0000u)};
        floatx2 W23 = {asf(ww.y << 16), asf(ww.y & 0xffff0000u)};
        floatx2 W45 = {asf(ww.z << 16), asf(ww.z & 0xffff0000u)};
        floatx2 W67 = {asf(ww.w << 16), asf(ww.w & 0xffff0000u)};

        const int dbase = (h * 32 + dd) * 8;
        float4 iva = *(const float4*)&v_s[dbase];
        float4 ivb = *(const float4*)&v_s[dbase + 4];
        float4 h0a = *(const float4*)&w_s[0][dbase];
        float4 h0b = *(const float4*)&w_s[0][dbase + 4];
        float4 h1a = *(const float4*)&w_s[1][dbase];
        float4 h1b = *(const float4*)&w_s[1][dbase + 4];

        #define PAIR(Wp, Hx, Hy, Ix, Iy, A)                                     \
        {                                                                       \
            floatx2 hh = {Hx, Hy};                                              \
            floatx2 ii = {Ix, Iy};                                              \
            floatx2 x = __builtin_elementwise_fma(hh, Wp, ii);                  \
            A = fmaf(x.x + x.y, __builtin_amdgcn_rcpf(x.x * x.y), A);           \
        }
        PAIR(W01, h0a.x, h0a.y, iva.x, iva.y, acc0)
        PAIR(W01, h1a.x, h1a.y, iva.x, iva.y, acc1)
        PAIR(W23, h0a.z, h0a.w, iva.z, iva.w, acc0)
        PAIR(W23, h1a.z, h1a.w, iva.z, iva.w, acc1)
        PAIR(W45, h0b.x, h0b.y, ivb.x, ivb.y, acc0)
        PAIR(W45, h1b.x, h1b.y, ivb.x, ivb.y, acc1)
        PAIR(W67, h0b.z, h0b.w, ivb.z, ivb.w, acc0)
        PAIR(W67, h1b.z, h1b.w, ivb.z, ivb.w, acc1)
        #undef PAIR
    }
    part[h][s] = make_float2(acc0, acc1);
    __syncthreads();

    float p0 = 0.f, p1 = 0.f;
    if (tid < 256) {
        float A0 = part[0][tid].x + part[1][tid].x;
        float A1 = part[0][tid].y + part[1][tid].y;
        float keep = 1.0f - (float)mask[b * S_ + tid];
        p0 = __builtin_amdgcn_exp2f(-C2F * A0) * keep;
        p1 = __builtin_amdgcn_exp2f(-C2F * A1) * keep;
        float s0 = p0, s1 = p1;
        #pragma unroll
        for (int off = 1; off < 64; off <<= 1) {
            s0 += __shfl_xor(s0, off);
            s1 += __shfl_xor(s1, off);
        }
        if ((tid & 63) == 0) wred[tid >> 6] = make_float2(s0, s1);
    }
    __syncthreads();

    if (tid < 256) {
        float den0 = wred[0].x + wred[1].x + wred[2].x + wred[3].x;
        float den1 = wred[0].y + wred[1].y + wred[2].y + wred[3].y;
        float a0 = p0 * __builtin_amdgcn_rcpf(den0);
        float a1 = p1 * __builtin_amdgcn_rcpf(den1);
        attn_out[(size_t)(b * T_ + t0 + 0) * S_ + tid] = a0;
        attn_out[(size_t)(b * T_ + t0 + 1) * S_ + tid] = a1;
        a_s[0][tid] = a0;
        a_s[1][tid] = a1;
    }
    __syncthreads();

    // out-projection: thread (dq=tid&127 -> d=4dq..4dq+3), s-quarter sq=tid>>7
    const int dq = tid & 127, sq = tid >> 7;
    const int sh = sq * 64;
    const unsigned short* cw = CWb + ((size_t)(b * S_) + sh) * D_ + 4 * dq;
    float m[TB][4] = {};
    #pragma unroll 8
    for (int s2 = 0; s2 < 64; ++s2) {
        uint2 cc = *(const uint2*)(cw + (size_t)s2 * D_);   // 8B coalesced
        float c0 = asf(cc.x << 16), c1 = asf(cc.x & 0xffff0000u);
        float c2 = asf(cc.y << 16), c3 = asf(cc.y & 0xffff0000u);
        #pragma unroll
        for (int t = 0; t < TB; ++t) {
            float a = a_s[t][sh + s2];
            m[t][0] = fmaf(a, c0, m[t][0]);
            m[t][1] = fmaf(a, c1, m[t][1]);
            m[t][2] = fmaf(a, c2, m[t][2]);
            m[t][3] = fmaf(a, c3, m[t][3]);
        }
    }
    #pragma unroll
    for (int t = 0; t < TB; ++t)
        *(float4*)&mixp[sq][t][4 * dq] = make_float4(m[t][0], m[t][1], m[t][2], m[t][3]);
    __syncthreads();

    {   // 512 threads cover TB*512 outputs (2 per thread)
        #pragma unroll
        for (int t = 0; t < TB; ++t) {
            const int d = tid;
            size_t idx = (size_t)(b * T_ + t0 + t) * D_ + d;
            out[idx] = mixp[0][t][d] + mixp[1][t][d] + mixp[2][t][d] + mixp[3][t][d]
                     + OB[idx];
        }
    }
}

extern "C" void kernel_launch(void* const* d_in, const int* in_sizes, int n_in,
                              void* d_out, int out_size, void* d_ws, size_t ws_size,
                              hipStream_t stream) {
    const float* output  = (const float*)d_in[0];
    const float* context = (const float*)d_in[1];
    const int*   mask    = (const int*)d_in[2];
    const float* Wq      = (const float*)d_in[3];
    const float* bq      = (const float*)d_in[4];
    const float* Wc      = (const float*)d_in[5];
    const float* v       = (const float*)d_in[6];
    const float* Wout    = (const float*)d_in[7];
    const float* bout    = (const float*)d_in[8];

    float* out  = (float*)d_out;                       // (B,T,D)
    float* attn = out + (size_t)B_ * T_ * D_;          // (B,T,S)

    char* ws = (char*)d_ws;
    float* Hb             = (float*)ws;                             // 2 MB
    float* OB             = (float*)(ws + (2u << 20));              // 2 MB
    unsigned short* Wb    = (unsigned short*)(ws + (4u << 20));     // 1 MB
    unsigned short* out_f = (unsigned short*)(ws + (6u << 20));     // 1 MB
    unsigned short* ctx_f = (unsigned short*)(ws + (7u << 20));     // 1 MB
    unsigned short* Wq_f  = (unsigned short*)(ws + (8u << 20));     // 0.5 MB
    unsigned short* Wc_f  = (unsigned short*)(ws + (8u << 20) + (512u << 10));
    unsigned short* WoT_f = (unsigned short*)(ws + (9u << 20));     // 0.5 MB
    unsigned short* WoB_f = (unsigned short*)(ws + (9u << 20) + (512u << 10));
    unsigned short* CWb   = (unsigned short*)(ws + (10u << 20));    // 1 MB

    dim3 blk(256);

    prep<<<dim3(16, 16, 6), blk, 0, stream>>>(
        output, context, Wq, Wc, Wout, out_f, ctx_f, Wq_f, Wc_f, WoT_f, WoB_f);

    // four independent GEMMs, one dispatch (z-slices), K=512 each:
    //   z0: Hb  = clamp(exp2(C2*(output@Wq + bq)))        [mode 1]
    //   z1: Wb  = bf16 clamp(exp2(C2*(context@Wc))/v)     [mode 3]
    //   z2: OB  = output@Wout_bot + bout                  [mode 4]
    //   z3: CWb = bf16 context@Wout_top                   [mode 5]
    GArgs gwq = { out_f, Wq_f,  bq,   Hb,  1 };
    GArgs guh = { ctx_f, Wc_f,  v,    Wb,  3 };
    GArgs gob = { out_f, WoB_f, bout, OB,  4 };
    GArgs gcw = { ctx_f, WoT_f, NULL, CWb, 5 };
    gemm2<<<dim3(8, 16, 4), blk, 0, stream>>>(gwq, guh, gob, gcw);

    attn_fused<<<dim3(B_ * T_ / TB), dim3(512), 0, stream>>>(
        Hb, Wb, CWb, OB, mask, v, attn, out);
}